// Round 2
// baseline (175.317 us; speedup 1.0000x reference)
//
#include <hip/hip_runtime.h>
#include <cstddef>

#define LDW 68   // padded LDS leading dim (floats)
#define NB  128  // grid size == #molecules/tokens (<= 256 CUs -> co-resident)

// ----------------------------------------------------------------------
// software grid barrier: per-launch one-shot counters (init kernel zeroes)
// ----------------------------------------------------------------------
__device__ __forceinline__ void gridbar(int* cnt) {
  __threadfence();
  __syncthreads();
  if (threadIdx.x == 0) {
    __hip_atomic_fetch_add(cnt, 1, __ATOMIC_ACQ_REL, __HIP_MEMORY_SCOPE_AGENT);
    while (__hip_atomic_load(cnt, __ATOMIC_ACQUIRE, __HIP_MEMORY_SCOPE_AGENT) < NB)
      __builtin_amdgcn_s_sleep(2);
  }
  __syncthreads();
  __threadfence();
}

__global__ void init_kernel(int* cnt) {
  if (threadIdx.x < 16) cnt[threadIdx.x] = 0;
}

// ----------------------------------------------------------------------
#define GNN_STEP(XC) { \
    float4 w0_ = *(const float4*)(wp); \
    float4 w1_ = *(const float4*)(wp + 4); \
    h0.x += (XC) * w0_.x; h0.y += (XC) * w0_.y; h0.z += (XC) * w0_.z; h0.w += (XC) * w0_.w; \
    h1.x += (XC) * w1_.x; h1.y += (XC) * w1_.y; h1.z += (XC) * w1_.z; h1.w += (XC) * w1_.w; \
    wp += LDW; }

#define ADJ_STEP(AC) { \
    float4 b0_ = *(const float4*)(hp); \
    float4 b1_ = *(const float4*)(hp + 4); \
    a0.x += (AC) * b0_.x; a0.y += (AC) * b0_.y; a0.z += (AC) * b0_.z; a0.w += (AC) * b0_.w; \
    a1.x += (AC) * b1_.x; a1.y += (AC) * b1_.y; a1.z += (AC) * b1_.z; a1.w += (AC) * b1_.w; \
    hp += LDW; }

__global__ __launch_bounds__(512, 2) void fused_kernel(
    const int* __restrict__ fp, const float* __restrict__ Aadj,
    const float* __restrict__ embed, const float* __restrict__ Wfp,
    const float* __restrict__ bfp, const float* __restrict__ fc_w,
    const float* __restrict__ fc_b,
    const float* __restrict__ qkv_w, const float* __restrict__ qkv_b,
    const float* __restrict__ out_w, const float* __restrict__ out_b,
    const float* __restrict__ ln1_s, const float* __restrict__ ln1_b,
    const float* __restrict__ ff1_w, const float* __restrict__ ff1_b,
    const float* __restrict__ ff2_w, const float* __restrict__ ff2_b,
    const float* __restrict__ ln2_s, const float* __restrict__ ln2_b,
    const float* __restrict__ Wout_w, const float* __restrict__ Wout_b,
    const float* __restrict__ Wprop_w, const float* __restrict__ Wprop_b,
    float* __restrict__ qq, int* __restrict__ cnt, float* __restrict__ out)
{
  // big region: GNN tiles, later re-carved for the transformer phase
  __shared__ __align__(16) float smem[3 * 64 * LDW];   // 52224 B
  __shared__ __align__(16) float red2[512];
  __shared__ __align__(16) float mol[64];
  __shared__ __align__(16) float vloc[64];   // token vector (persists)
  __shared__ __align__(16) float vloc2[64];  // post-LN1 vector
  __shared__ float w8[16], w8b[16];

  const int b   = blockIdx.x;
  const int tid = threadIdx.x;

  // ========================= GNN phase =========================
  {
    float* xs  = smem;                 // [64][LDW]
    float* hsb = smem + 64 * LDW;      // [64][LDW]
    float* Ws  = smem + 2 * 64 * LDW;  // [64][LDW]  W transposed
    const int row = tid >> 3;
    const int o0  = (tid & 7) * 8;

    for (int idx = tid; idx < 4096; idx += 512) {
      int r = idx >> 6, c = idx & 63;
      xs[r * LDW + c] = embed[(size_t)fp[b * 64 + r] * 64 + c];
    }
    float4 Areg[16];
    {
      const float4* arow =
          (const float4*)(Aadj + (size_t)(b * 64 + row) * 8192 + (size_t)b * 64);
#pragma unroll
      for (int q = 0; q < 16; ++q) Areg[q] = arow[q];
    }

    for (int l = 0; l < 3; ++l) {
      for (int idx = tid; idx < 4096; idx += 512) {
        int o = idx & 63, k = idx >> 6;
        Ws[k * LDW + o] = Wfp[l * 4096 + o * 64 + k];
      }
      __syncthreads();

      float4 xr[16];
#pragma unroll
      for (int q = 0; q < 16; ++q)
        xr[q] = *(const float4*)&xs[row * LDW + 4 * q];

      float4 h0 = *(const float4*)&bfp[l * 64 + o0];
      float4 h1 = *(const float4*)&bfp[l * 64 + o0 + 4];
      {
        const float* wp = &Ws[o0];
#pragma unroll
        for (int k4 = 0; k4 < 16; ++k4) {
          float4 xv = xr[k4];
          GNN_STEP(xv.x) GNN_STEP(xv.y) GNN_STEP(xv.z) GNN_STEP(xv.w)
        }
      }
      h0.x = fmaxf(h0.x, 0.f); h0.y = fmaxf(h0.y, 0.f);
      h0.z = fmaxf(h0.z, 0.f); h0.w = fmaxf(h0.w, 0.f);
      h1.x = fmaxf(h1.x, 0.f); h1.y = fmaxf(h1.y, 0.f);
      h1.z = fmaxf(h1.z, 0.f); h1.w = fmaxf(h1.w, 0.f);
      *(float4*)&hsb[row * LDW + o0]     = h0;
      *(float4*)&hsb[row * LDW + o0 + 4] = h1;
      __syncthreads();

      float4 a0 = h0, a1 = h1;
      {
        const float* hp = &hsb[o0];
#pragma unroll
        for (int j4 = 0; j4 < 16; ++j4) {
          float4 av = Areg[j4];
          ADJ_STEP(av.x) ADJ_STEP(av.y) ADJ_STEP(av.z) ADJ_STEP(av.w)
        }
      }
      float ss = a0.x*a0.x + a0.y*a0.y + a0.z*a0.z + a0.w*a0.w
               + a1.x*a1.x + a1.y*a1.y + a1.z*a1.z + a1.w*a1.w;
      ss += __shfl_xor(ss, 1); ss += __shfl_xor(ss, 2); ss += __shfl_xor(ss, 4);
      float inv = 1.0f / fmaxf(sqrtf(ss), 1e-12f);
      a0.x *= inv; a0.y *= inv; a0.z *= inv; a0.w *= inv;
      a1.x *= inv; a1.y *= inv; a1.z *= inv; a1.w *= inv;
      *(float4*)&xs[row * LDW + o0]     = a0;
      *(float4*)&xs[row * LDW + o0 + 4] = a1;
      __syncthreads();
    }

    // pool + fc -> vloc
    {
      int c = tid & 63, part = tid >> 6;
      float ps = 0.f;
#pragma unroll
      for (int r = 0; r < 8; ++r) ps += xs[(part * 8 + r) * LDW + c];
      red2[part * 64 + c] = ps;
    }
    __syncthreads();
    if (tid < 64) {
      float m = 0.f;
#pragma unroll
      for (int p = 0; p < 8; ++p) m += red2[p * 64 + tid];
      mol[tid] = m;
    }
    __syncthreads();
    if (tid < 64) {
      float a = fc_b[tid];
      const float* wr = fc_w + tid * 64;
#pragma unroll 8
      for (int k = 0; k < 64; ++k) a += mol[k] * wr[k];
      vloc[tid] = a;
    }
    __syncthreads();
  }

  // ================== transformer phase (LDS re-carve) ==================
  float* Pl   = smem;          // [4][132]
  float* cb   = smem + 528;    // [2048]
  float* redt = smem + 2576;   // [512]
  float* qloc = smem + 3088;   // [192]
  float* osh  = smem + 3280;   // [64]
  float* ffp  = smem + 3344;   // [64]

  for (int l = 0; l < 2; ++l) {
    // ---- qkv for OWN token ----
    if (tid < 192) {
      const float4* wr = (const float4*)(qkv_w + (size_t)l * 12288 + tid * 64);
      float a = qkv_b[l * 192 + tid];
#pragma unroll
      for (int k4 = 0; k4 < 16; ++k4) {
        float4 w4 = wr[k4];
        float4 x4 = *(const float4*)&vloc[k4 * 4];
        a += w4.x * x4.x + w4.y * x4.y + w4.z * x4.z + w4.w * x4.w;
      }
      qloc[tid] = a;
      qq[(size_t)l * NB * 192 + (size_t)b * 192 + tid] = a;
    }
    gridbar(cnt + l);   // all tokens' qkv visible after this

    const float* KV = qq + (size_t)l * NB * 192;

    // ---- scores + softmax: thread = (j, h) ----
    {
      const int j = tid & 127, h = tid >> 7;
      const float4* qp = (const float4*)&qloc[h * 16];
      const float4* kp = (const float4*)(KV + j * 192 + 64 + h * 16);
      float s = 0.f;
#pragma unroll
      for (int t = 0; t < 4; ++t) {
        float4 a4 = qp[t], b4 = kp[t];
        s += a4.x * b4.x + a4.y * b4.y + a4.z * b4.z + a4.w * b4.w;
      }
      s *= 0.25f;  // 1/sqrt(16)
      float mm = s;
      for (int off = 32; off; off >>= 1) mm = fmaxf(mm, __shfl_xor(mm, off));
      if ((tid & 63) == 0) w8[tid >> 6] = mm;
      __syncthreads();
      float M = fmaxf(w8[2 * h], w8[2 * h + 1]);
      float e = expf(s - M);
      float sm = e;
      for (int off = 32; off; off >>= 1) sm += __shfl_xor(sm, off);
      if ((tid & 63) == 0) w8b[tid >> 6] = sm;
      __syncthreads();
      Pl[h * 132 + j] = e / (w8b[2 * h] + w8b[2 * h + 1]);
    }
    __syncthreads();

    // ---- PV: thread = (d, j-chunk) ----
    {
      const int d = tid & 63, part = tid >> 6, h2 = d >> 4;
      float a = 0.f;
#pragma unroll
      for (int jj = 0; jj < 16; ++jj) {
        int j2 = part * 16 + jj;
        a += Pl[h2 * 132 + j2] * KV[j2 * 192 + 128 + d];
      }
      redt[part * 64 + d] = a;
    }
    __syncthreads();
    if (tid < 64) {
      float o = 0.f;
#pragma unroll
      for (int p = 0; p < 8; ++p) o += redt[p * 64 + tid];
      osh[tid] = o;
    }
    __syncthreads();

    // ---- out-proj + residual + LN1 ----
    if (tid < 64) {
      const int d = tid;
      float a = out_b[l * 64 + d];
      const float* wr = out_w + (size_t)l * 4096 + d * 64;
#pragma unroll 8
      for (int c = 0; c < 64; ++c) a += osh[c] * wr[c];
      float r = vloc[d] + a;
      float mu = r;
      for (int off = 32; off; off >>= 1) mu += __shfl_xor(mu, off);
      mu *= (1.0f / 64.0f);
      float df = r - mu;
      float var = df * df;
      for (int off = 32; off; off >>= 1) var += __shfl_xor(var, off);
      var *= (1.0f / 64.0f);
      vloc2[d] = df / sqrtf(var + 1e-5f) * ln1_s[l * 64 + d] + ln1_b[l * 64 + d];
    }
    __syncthreads();

    // ---- FF phase 1: coalesced w1 read, 16-lane shuffle dot ----
    {
      const float4* w1f = (const float4*)(ff1_w + (size_t)l * 131072);
      const int lane16 = tid & 15;
      const float4 vv = *(const float4*)&vloc2[lane16 * 4];
      for (int it = 0; it < 64; ++it) {
        int f = tid + 512 * it;
        float4 wv = w1f[f];
        float p = wv.x * vv.x + wv.y * vv.y + wv.z * vv.z + wv.w * vv.w;
        p += __shfl_xor(p, 1); p += __shfl_xor(p, 2);
        p += __shfl_xor(p, 4); p += __shfl_xor(p, 8);
        if (lane16 == 0) {
          int j = f >> 4;
          cb[j] = fmaxf(p + ff1_b[l * 2048 + j], 0.f);
        }
      }
    }
    __syncthreads();

    // ---- FF phase 2: wave w owns rows d = w*8..w*8+7, coalesced w2 read ----
    {
      const int w = tid >> 6, lane = tid & 63;
      const float4* w2f = (const float4*)(ff2_w + (size_t)l * 131072);
      const float4* cbf = (const float4*)cb;
#pragma unroll
      for (int rr = 0; rr < 8; ++rr) {
        int d = w * 8 + rr;
        float p = 0.f;
#pragma unroll
        for (int it = 0; it < 8; ++it) {
          int f = it * 64 + lane;
          float4 wv = w2f[d * 512 + f];
          float4 cv = cbf[f];
          p += wv.x * cv.x + wv.y * cv.y + wv.z * cv.z + wv.w * cv.w;
        }
        for (int off = 32; off; off >>= 1) p += __shfl_xor(p, off);
        if (lane == 0) ffp[d] = p;
      }
    }
    __syncthreads();

    // ---- residual + LN2 -> vloc ----
    if (tid < 64) {
      const int d = tid;
      float r = vloc2[d] + ffp[d] + ff2_b[l * 64 + d];
      float mu = r;
      for (int off = 32; off; off >>= 1) mu += __shfl_xor(mu, off);
      mu *= (1.0f / 64.0f);
      float df = r - mu;
      float var = df * df;
      for (int off = 32; off; off >>= 1) var += __shfl_xor(var, off);
      var *= (1.0f / 64.0f);
      vloc[d] = df / sqrtf(var + 1e-5f) * ln2_s[l * 64 + d] + ln2_b[l * 64 + d];
    }
    __syncthreads();
  }

  // ========================= output head =========================
  {
    float* hh0 = redt;        // reuse
    float* hh1 = redt + 64;
    if (tid < 64) {
      float a = Wout_b[tid];
      const float* wr = Wout_w + tid * 64;
#pragma unroll 8
      for (int c = 0; c < 64; ++c) a += vloc[c] * wr[c];
      hh0[tid] = fmaxf(a, 0.f);
    }
    __syncthreads();
    if (tid < 64) {
      float a = Wout_b[64 + tid];
      const float* wr = Wout_w + 4096 + tid * 64;
#pragma unroll 8
      for (int c = 0; c < 64; ++c) a += hh0[c] * wr[c];
      hh1[tid] = fmaxf(a, 0.f);
    }
    __syncthreads();
    if (tid < 2) {
      float a = Wprop_b[tid];
      const float* wr = Wprop_w + tid * 64;
#pragma unroll 8
      for (int c = 0; c < 64; ++c) a += hh1[c] * wr[c];
      out[b * 2 + tid] = a;
    }
  }
}

// ======================================================================
extern "C" void kernel_launch(void* const* d_in, const int* in_sizes, int n_in,
                              void* d_out, int out_size, void* d_ws, size_t ws_size,
                              hipStream_t stream) {
  const int*   fp      = (const int*)  d_in[0];
  const float* Aadj    = (const float*)d_in[1];
  const float* embed   = (const float*)d_in[2];
  const float* Wfp     = (const float*)d_in[3];
  const float* bfp     = (const float*)d_in[4];
  const float* fc_w    = (const float*)d_in[5];
  const float* fc_b    = (const float*)d_in[6];
  const float* qkv_w   = (const float*)d_in[7];
  const float* qkv_b   = (const float*)d_in[8];
  const float* out_w   = (const float*)d_in[9];
  const float* out_b   = (const float*)d_in[10];
  const float* ln1_s   = (const float*)d_in[11];
  const float* ln1_b   = (const float*)d_in[12];
  const float* ff1_w   = (const float*)d_in[13];
  const float* ff1_b   = (const float*)d_in[14];
  const float* ff2_w   = (const float*)d_in[15];
  const float* ff2_b   = (const float*)d_in[16];
  const float* ln2_s   = (const float*)d_in[17];
  const float* ln2_b   = (const float*)d_in[18];
  const float* Wout_w  = (const float*)d_in[19];
  const float* Wout_b  = (const float*)d_in[20];
  const float* Wprop_w = (const float*)d_in[21];
  const float* Wprop_b = (const float*)d_in[22];
  float* out = (float*)d_out;

  int*   cnt = (int*)d_ws;                 // 16 ints of barrier counters
  float* qq  = (float*)d_ws + 64;          // 2 x [128][192] qkv buffers

  init_kernel<<<dim3(1), dim3(64), 0, stream>>>(cnt);
  fused_kernel<<<dim3(NB), dim3(512), 0, stream>>>(
      fp, Aadj, embed, Wfp, bfp, fc_w, fc_b,
      qkv_w, qkv_b, out_w, out_b, ln1_s, ln1_b,
      ff1_w, ff1_b, ff2_w, ff2_b, ln2_s, ln2_b,
      Wout_w, Wout_b, Wprop_w, Wprop_b, qq, cnt, out);
}

// Round 3
// 100.058 us; speedup vs baseline: 1.7522x; 1.7522x over previous
//
#include <hip/hip_runtime.h>
#include <cstddef>

#define LDW 68   // padded LDS leading dim (floats)
#define NB  128  // #molecules / tokens

// ----------------------------------------------------------------------
#define GNN_STEP(XC) { \
    float4 w0_ = *(const float4*)(wp); \
    float4 w1_ = *(const float4*)(wp + 4); \
    h0.x += (XC) * w0_.x; h0.y += (XC) * w0_.y; h0.z += (XC) * w0_.z; h0.w += (XC) * w0_.w; \
    h1.x += (XC) * w1_.x; h1.y += (XC) * w1_.y; h1.z += (XC) * w1_.z; h1.w += (XC) * w1_.w; \
    wp += LDW; }

#define ADJ_STEP(AC) { \
    float4 b0_ = *(const float4*)(hp); \
    float4 b1_ = *(const float4*)(hp + 4); \
    a0.x += (AC) * b0_.x; a0.y += (AC) * b0_.y; a0.z += (AC) * b0_.z; a0.w += (AC) * b0_.w; \
    a1.x += (AC) * b1_.x; a1.y += (AC) * b1_.y; a1.z += (AC) * b1_.z; a1.w += (AC) * b1_.w; \
    hp += LDW; }

// ======================================================================
// K1: GNN + pool + fc + qkv(layer 0).  grid=128, block=512
// ======================================================================
__global__ __launch_bounds__(512, 2) void gnn_kernel(
    const int* __restrict__ fp, const float* __restrict__ Aadj,
    const float* __restrict__ embed, const float* __restrict__ Wfp,
    const float* __restrict__ bfp, const float* __restrict__ fc_w,
    const float* __restrict__ fc_b,
    const float* __restrict__ qkv_w, const float* __restrict__ qkv_b,
    float* __restrict__ vout, float* __restrict__ qqout)
{
  __shared__ __align__(16) float smem[3 * 64 * LDW];
  __shared__ __align__(16) float red2[512];
  __shared__ __align__(16) float mol[64];
  __shared__ __align__(16) float vloc[64];

  float* xs  = smem;                 // [64][LDW]
  float* hsb = smem + 64 * LDW;      // [64][LDW] (first used to stage A block)
  float* Ws  = smem + 2 * 64 * LDW;  // [64][LDW]  W transposed

  const int b   = blockIdx.x;
  const int tid = threadIdx.x;
  const int row = tid >> 3;
  const int o0  = (tid & 7) * 8;

  // x0 = embed[fingerprints]
  for (int idx = tid; idx < 4096; idx += 512) {
    int r = idx >> 6, c = idx & 63;
    xs[r * LDW + c] = embed[(size_t)fp[b * 64 + r] * 64 + c];
  }
  // stage adjacency diagonal block into LDS (coalesced, read ONCE from L2)
  for (int idx = tid; idx < 1024; idx += 512) {
    int r = idx >> 4, q = idx & 15;
    ((float4*)hsb)[idx] =
        ((const float4*)(Aadj + (size_t)(b * 64 + r) * 8192 + (size_t)b * 64))[q];
  }
  __syncthreads();
  float4 Areg[16];
#pragma unroll
  for (int q = 0; q < 16; ++q)
    Areg[q] = ((const float4*)(hsb + row * 64))[q];   // 8-way broadcast reads

  for (int l = 0; l < 3; ++l) {
    for (int idx = tid; idx < 4096; idx += 512) {
      int o = idx & 63, k = idx >> 6;
      Ws[k * LDW + o] = Wfp[l * 4096 + o * 64 + k];
    }
    __syncthreads();   // also guards Areg reads / xs writes of prev layer

    float4 xr[16];
#pragma unroll
    for (int q = 0; q < 16; ++q)
      xr[q] = *(const float4*)&xs[row * LDW + 4 * q];

    float4 h0 = *(const float4*)&bfp[l * 64 + o0];
    float4 h1 = *(const float4*)&bfp[l * 64 + o0 + 4];
    {
      const float* wp = &Ws[o0];
#pragma unroll
      for (int k4 = 0; k4 < 16; ++k4) {
        float4 xv = xr[k4];
        GNN_STEP(xv.x) GNN_STEP(xv.y) GNN_STEP(xv.z) GNN_STEP(xv.w)
      }
    }
    h0.x = fmaxf(h0.x, 0.f); h0.y = fmaxf(h0.y, 0.f);
    h0.z = fmaxf(h0.z, 0.f); h0.w = fmaxf(h0.w, 0.f);
    h1.x = fmaxf(h1.x, 0.f); h1.y = fmaxf(h1.y, 0.f);
    h1.z = fmaxf(h1.z, 0.f); h1.w = fmaxf(h1.w, 0.f);
    *(float4*)&hsb[row * LDW + o0]     = h0;
    *(float4*)&hsb[row * LDW + o0 + 4] = h1;
    __syncthreads();

    float4 a0 = h0, a1 = h1;
    {
      const float* hp = &hsb[o0];
#pragma unroll
      for (int j4 = 0; j4 < 16; ++j4) {
        float4 av = Areg[j4];
        ADJ_STEP(av.x) ADJ_STEP(av.y) ADJ_STEP(av.z) ADJ_STEP(av.w)
      }
    }
    float ss = a0.x*a0.x + a0.y*a0.y + a0.z*a0.z + a0.w*a0.w
             + a1.x*a1.x + a1.y*a1.y + a1.z*a1.z + a1.w*a1.w;
    ss += __shfl_xor(ss, 1); ss += __shfl_xor(ss, 2); ss += __shfl_xor(ss, 4);
    float inv = 1.0f / fmaxf(sqrtf(ss), 1e-12f);
    a0.x *= inv; a0.y *= inv; a0.z *= inv; a0.w *= inv;
    a1.x *= inv; a1.y *= inv; a1.z *= inv; a1.w *= inv;
    *(float4*)&xs[row * LDW + o0]     = a0;
    *(float4*)&xs[row * LDW + o0 + 4] = a1;
    __syncthreads();
  }

  // pool + fc -> vloc
  {
    int c = tid & 63, part = tid >> 6;
    float ps = 0.f;
#pragma unroll
    for (int r = 0; r < 8; ++r) ps += xs[(part * 8 + r) * LDW + c];
    red2[part * 64 + c] = ps;
  }
  __syncthreads();
  if (tid < 64) {
    float m = 0.f;
#pragma unroll
    for (int p = 0; p < 8; ++p) m += red2[p * 64 + tid];
    mol[tid] = m;
  }
  __syncthreads();
  if (tid < 64) {
    float a = fc_b[tid];
    const float* wr = fc_w + tid * 64;
#pragma unroll 8
    for (int k = 0; k < 64; ++k) a += mol[k] * wr[k];
    vloc[tid] = a;
    vout[b * 64 + tid] = a;
  }
  __syncthreads();

  // qkv for layer 0 (all tokens' qkv ready at kernel boundary = free barrier)
  if (tid < 192) {
    const float4* wr = (const float4*)(qkv_w + tid * 64);
    float a = qkv_b[tid];
#pragma unroll
    for (int k4 = 0; k4 < 16; ++k4) {
      float4 w4 = wr[k4];
      float4 x4 = *(const float4*)&vloc[k4 * 4];
      a += w4.x * x4.x + w4.y * x4.y + w4.z * x4.z + w4.w * x4.w;
    }
    qqout[(size_t)b * 192 + tid] = a;
  }
}

// ======================================================================
// K2/K3: attention + FF for one layer; then either next-layer qkv or head.
// grid=128 (token), block=512
// ======================================================================
template <bool LAST>
__global__ __launch_bounds__(512) void layer_kernel(
    const float* __restrict__ vin, const float* __restrict__ qq_in,
    const float* __restrict__ out_w, const float* __restrict__ out_b,
    const float* __restrict__ ln1_s, const float* __restrict__ ln1_b,
    const float* __restrict__ ff1_w, const float* __restrict__ ff1_b,
    const float* __restrict__ ff2_w, const float* __restrict__ ff2_b,
    const float* __restrict__ ln2_s, const float* __restrict__ ln2_b,
    const float* __restrict__ nqkv_w, const float* __restrict__ nqkv_b,
    float* __restrict__ qq_out,
    const float* __restrict__ Wout_w, const float* __restrict__ Wout_b,
    const float* __restrict__ Wprop_w, const float* __restrict__ Wprop_b,
    float* __restrict__ vout)
{
  __shared__ __align__(16) float qloc[192];
  __shared__ __align__(16) float Pl[4 * 132];
  __shared__ __align__(16) float cb[2048];
  __shared__ __align__(16) float redt[512];
  __shared__ __align__(16) float vloc[64];
  __shared__ __align__(16) float vloc2[64];
  __shared__ __align__(16) float osh[64];
  __shared__ __align__(16) float ffp[64];
  __shared__ float w8[8], w8b[8];

  const int b   = blockIdx.x;
  const int tid = threadIdx.x;

  if (tid < 64)  vloc[tid] = vin[b * 64 + tid];
  if (tid < 192) qloc[tid] = qq_in[(size_t)b * 192 + tid];
  __syncthreads();

  // ---- scores + softmax: thread = (j, h) ----
  {
    const int j = tid & 127, h = tid >> 7;
    const float4* qp = (const float4*)&qloc[h * 16];
    const float4* kp = (const float4*)(qq_in + (size_t)j * 192 + 64 + h * 16);
    float s = 0.f;
#pragma unroll
    for (int t = 0; t < 4; ++t) {
      float4 a4 = qp[t], b4 = kp[t];
      s += a4.x * b4.x + a4.y * b4.y + a4.z * b4.z + a4.w * b4.w;
    }
    s *= 0.25f;  // 1/sqrt(16)
    float mm = s;
    for (int off = 32; off; off >>= 1) mm = fmaxf(mm, __shfl_xor(mm, off));
    if ((tid & 63) == 0) w8[tid >> 6] = mm;
    __syncthreads();
    float M = fmaxf(w8[2 * h], w8[2 * h + 1]);
    float e = expf(s - M);
    float sm = e;
    for (int off = 32; off; off >>= 1) sm += __shfl_xor(sm, off);
    if ((tid & 63) == 0) w8b[tid >> 6] = sm;
    __syncthreads();
    Pl[h * 132 + j] = e / (w8b[2 * h] + w8b[2 * h + 1]);
  }
  __syncthreads();

  // ---- PV: thread = (d, j-chunk) ----
  {
    const int d = tid & 63, part = tid >> 6, h2 = d >> 4;
    float a = 0.f;
#pragma unroll
    for (int jj = 0; jj < 16; ++jj) {
      int j2 = part * 16 + jj;
      a += Pl[h2 * 132 + j2] * qq_in[(size_t)j2 * 192 + 128 + d];
    }
    redt[part * 64 + d] = a;
  }
  __syncthreads();
  if (tid < 64) {
    float o = 0.f;
#pragma unroll
    for (int p = 0; p < 8; ++p) o += redt[p * 64 + tid];
    osh[tid] = o;
  }
  __syncthreads();

  // ---- out-proj + residual + LN1 ----
  if (tid < 64) {
    const int d = tid;
    float a = out_b[d];
    const float* wr = out_w + d * 64;
#pragma unroll 8
    for (int c = 0; c < 64; ++c) a += osh[c] * wr[c];
    float r = vloc[d] + a;
    float mu = r;
    for (int off = 32; off; off >>= 1) mu += __shfl_xor(mu, off);
    mu *= (1.0f / 64.0f);
    float df = r - mu;
    float var = df * df;
    for (int off = 32; off; off >>= 1) var += __shfl_xor(var, off);
    var *= (1.0f / 64.0f);
    vloc2[d] = df / sqrtf(var + 1e-5f) * ln1_s[d] + ln1_b[d];
  }
  __syncthreads();

  // ---- FF phase 1: coalesced w1 read, 16-lane shuffle dot ----
  {
    const float4* w1f = (const float4*)ff1_w;
    const int lane16 = tid & 15;
    const float4 vv = *(const float4*)&vloc2[lane16 * 4];
    for (int it = 0; it < 64; ++it) {
      int f = tid + 512 * it;
      float4 wv = w1f[f];
      float p = wv.x * vv.x + wv.y * vv.y + wv.z * vv.z + wv.w * vv.w;
      p += __shfl_xor(p, 1); p += __shfl_xor(p, 2);
      p += __shfl_xor(p, 4); p += __shfl_xor(p, 8);
      if (lane16 == 0) {
        int j = f >> 4;
        cb[j] = fmaxf(p + ff1_b[j], 0.f);
      }
    }
  }
  __syncthreads();

  // ---- FF phase 2: wave w owns rows d = w*8..w*8+7, coalesced w2 read ----
  {
    const int w = tid >> 6, lane = tid & 63;
    const float4* w2f = (const float4*)ff2_w;
    const float4* cbf = (const float4*)cb;
#pragma unroll
    for (int rr = 0; rr < 8; ++rr) {
      int d = w * 8 + rr;
      float p = 0.f;
#pragma unroll
      for (int it = 0; it < 8; ++it) {
        int f = it * 64 + lane;
        float4 wv = w2f[d * 512 + f];
        float4 cv = cbf[f];
        p += wv.x * cv.x + wv.y * cv.y + wv.z * cv.z + wv.w * cv.w;
      }
      for (int off = 32; off; off >>= 1) p += __shfl_xor(p, off);
      if (lane == 0) ffp[d] = p;
    }
  }
  __syncthreads();

  // ---- residual + LN2 -> vloc ----
  if (tid < 64) {
    const int d = tid;
    float r = vloc2[d] + ffp[d] + ff2_b[d];
    float mu = r;
    for (int off = 32; off; off >>= 1) mu += __shfl_xor(mu, off);
    mu *= (1.0f / 64.0f);
    float df = r - mu;
    float var = df * df;
    for (int off = 32; off; off >>= 1) var += __shfl_xor(var, off);
    var *= (1.0f / 64.0f);
    vloc[d] = df / sqrtf(var + 1e-5f) * ln2_s[d] + ln2_b[d];
  }
  __syncthreads();

  if (!LAST) {
    // next-layer qkv; write v_next
    if (tid < 64) vout[b * 64 + tid] = vloc[tid];
    if (tid < 192) {
      const float4* wr = (const float4*)(nqkv_w + tid * 64);
      float a = nqkv_b[tid];
#pragma unroll
      for (int k4 = 0; k4 < 16; ++k4) {
        float4 w4 = wr[k4];
        float4 x4 = *(const float4*)&vloc[k4 * 4];
        a += w4.x * x4.x + w4.y * x4.y + w4.z * x4.z + w4.w * x4.w;
      }
      qq_out[(size_t)b * 192 + tid] = a;
    }
  } else {
    // output head
    float* hh0 = redt;
    float* hh1 = redt + 64;
    if (tid < 64) {
      float a = Wout_b[tid];
      const float* wr = Wout_w + tid * 64;
#pragma unroll 8
      for (int c = 0; c < 64; ++c) a += vloc[c] * wr[c];
      hh0[tid] = fmaxf(a, 0.f);
    }
    __syncthreads();
    if (tid < 64) {
      float a = Wout_b[64 + tid];
      const float* wr = Wout_w + 4096 + tid * 64;
#pragma unroll 8
      for (int c = 0; c < 64; ++c) a += hh0[c] * wr[c];
      hh1[tid] = fmaxf(a, 0.f);
    }
    __syncthreads();
    if (tid < 2) {
      float a = Wprop_b[tid];
      const float* wr = Wprop_w + tid * 64;
#pragma unroll 8
      for (int c = 0; c < 64; ++c) a += hh1[c] * wr[c];
      vout[b * 2 + tid] = a;
    }
  }
}

// ======================================================================
extern "C" void kernel_launch(void* const* d_in, const int* in_sizes, int n_in,
                              void* d_out, int out_size, void* d_ws, size_t ws_size,
                              hipStream_t stream) {
  const int*   fp      = (const int*)  d_in[0];
  const float* Aadj    = (const float*)d_in[1];
  const float* embed   = (const float*)d_in[2];
  const float* Wfp     = (const float*)d_in[3];
  const float* bfp     = (const float*)d_in[4];
  const float* fc_w    = (const float*)d_in[5];
  const float* fc_b    = (const float*)d_in[6];
  const float* qkv_w   = (const float*)d_in[7];
  const float* qkv_b   = (const float*)d_in[8];
  const float* out_w   = (const float*)d_in[9];
  const float* out_b   = (const float*)d_in[10];
  const float* ln1_s   = (const float*)d_in[11];
  const float* ln1_b   = (const float*)d_in[12];
  const float* ff1_w   = (const float*)d_in[13];
  const float* ff1_b   = (const float*)d_in[14];
  const float* ff2_w   = (const float*)d_in[15];
  const float* ff2_b   = (const float*)d_in[16];
  const float* ln2_s   = (const float*)d_in[17];
  const float* ln2_b   = (const float*)d_in[18];
  const float* Wout_w  = (const float*)d_in[19];
  const float* Wout_b  = (const float*)d_in[20];
  const float* Wprop_w = (const float*)d_in[21];
  const float* Wprop_b = (const float*)d_in[22];
  float* out = (float*)d_out;

  float* ws  = (float*)d_ws;
  float* v0  = ws;            // [128][64]
  float* v1  = ws + 8192;     // [128][64]
  float* qq0 = ws + 16384;    // [128][192]
  float* qq1 = ws + 16384 + NB * 192;

  gnn_kernel<<<dim3(NB), dim3(512), 0, stream>>>(
      fp, Aadj, embed, Wfp, bfp, fc_w, fc_b, qkv_w, qkv_b, v0, qq0);

  layer_kernel<false><<<dim3(NB), dim3(512), 0, stream>>>(
      v0, qq0, out_w, out_b, ln1_s, ln1_b,
      ff1_w, ff1_b, ff2_w, ff2_b, ln2_s, ln2_b,
      qkv_w + 12288, qkv_b + 192, qq1,
      nullptr, nullptr, nullptr, nullptr, v1);

  layer_kernel<true><<<dim3(NB), dim3(512), 0, stream>>>(
      v1, qq1, out_w + 4096, out_b + 64, ln1_s + 64, ln1_b + 64,
      ff1_w + 131072, ff1_b + 2048, ff2_w + 131072, ff2_b + 64,
      ln2_s + 64, ln2_b + 64,
      nullptr, nullptr, nullptr,
      Wout_w, Wout_b, Wprop_w, Wprop_b, out);
}

// Round 4
// 68.063 us; speedup vs baseline: 2.5758x; 1.4701x over previous
//
#include <hip/hip_runtime.h>
#include <cstddef>

#define NB 128   // #molecules / tokens

// ======================================================================
// K1: blocks 0..127: GNN + pool + fc + qkv(layer0).  blocks 128..191:
// transpose ff1_w -> wT1 (runs on otherwise-idle CUs).  block=256.
// ======================================================================
__global__ __launch_bounds__(256) void gnn_kernel(
    const int* __restrict__ fp, const float* __restrict__ Aadj,
    const float* __restrict__ embed, const float* __restrict__ Wfp,
    const float* __restrict__ bfp, const float* __restrict__ fc_w,
    const float* __restrict__ fc_b,
    const float* __restrict__ qkv_w, const float* __restrict__ qkv_b,
    const float* __restrict__ ff1_w, float* __restrict__ wT1,
    float* __restrict__ vout, float* __restrict__ qqout)
{
  __shared__ __align__(16) float xT[64 * 68];    // [feat k][atom]
  __shared__ __align__(16) float hR[64 * 68];    // [atom][feat]
  __shared__ __align__(16) float WT[64 * 68];    // [k][o]  (W transposed)
  __shared__ __align__(16) float Ablk[64 * 64];  // [i][j] symmetric
  __shared__ float prt[64 * 17];
  __shared__ float inv64[64];
  __shared__ float red[256];
  __shared__ __align__(16) float mol[64];
  __shared__ __align__(16) float vloc[64];

  const int bid = blockIdx.x;
  const int tid = threadIdx.x;

  // ---------------- transpose blocks ----------------
  if (bid >= NB) {
    const int t = bid - NB;            // 0..63
    const int l = t >> 5, j0 = (t & 31) * 64;
    const float* src = ff1_w + (size_t)l * 131072;
    float*       dst = wT1  + (size_t)l * 131072;
#pragma unroll
    for (int q = 0; q < 4; ++q) {      // read coalesced rows j
      int jr = (tid >> 4) + 16 * q, kq = tid & 15;
      float4 vv = *(const float4*)(src + (size_t)(j0 + jr) * 64 + kq * 4);
      *(float4*)&xT[jr * 68 + kq * 4] = vv;
    }
    __syncthreads();
#pragma unroll
    for (int q = 0; q < 4; ++q) {      // write coalesced rows k
      int kr = (tid >> 4) + 16 * q, jq = tid & 15;
      float4 ov;
      ov.x = xT[(jq * 4 + 0) * 68 + kr];
      ov.y = xT[(jq * 4 + 1) * 68 + kr];
      ov.z = xT[(jq * 4 + 2) * 68 + kr];
      ov.w = xT[(jq * 4 + 3) * 68 + kr];
      *(float4*)(dst + (size_t)kr * 2048 + j0 + jq * 4) = ov;
    }
    return;
  }

  // ---------------- GNN blocks ----------------
  const int b  = bid;
  const int rg = tid & 15, cg = tid >> 4;   // 16 row-groups x 16 col-groups
  const int r0 = rg * 4,   c0 = cg * 4;

  // x0 = embed[fingerprints], stored transposed
  for (int idx = tid; idx < 4096; idx += 256) {
    int r = idx >> 6, c = idx & 63;
    xT[c * 68 + r] = embed[(size_t)fp[b * 64 + r] * 64 + c];
  }
  // adjacency diagonal block (row-major; symmetric)
  for (int idx = tid; idx < 1024; idx += 256) {
    int r = idx >> 4, q = idx & 15;
    *(float4*)&Ablk[r * 64 + q * 4] =
        *(const float4*)(Aadj + (size_t)(b * 64 + r) * 8192 + b * 64 + q * 4);
  }

  for (int l = 0; l < 3; ++l) {
    // stage W transposed: WT[k][o] = Wfp[l][o][k]  (coalesced read)
    for (int idx = tid; idx < 4096; idx += 256) {
      int o = idx >> 6, k = idx & 63;
      WT[k * 68 + o] = Wfp[l * 4096 + o * 64 + k];
    }
    __syncthreads();

    // h tile = relu(x @ W^T + b): acc_i[c] = sum_k x[r0+i][k] * W[c0+c][k]
    float4 bb = *(const float4*)&bfp[l * 64 + c0];
    float4 acc0 = bb, acc1 = bb, acc2 = bb, acc3 = bb;
#pragma unroll 8
    for (int k = 0; k < 64; ++k) {
      float4 xv = *(const float4*)&xT[k * 68 + r0];
      float4 wv = *(const float4*)&WT[k * 68 + c0];
      acc0.x += xv.x * wv.x; acc0.y += xv.x * wv.y; acc0.z += xv.x * wv.z; acc0.w += xv.x * wv.w;
      acc1.x += xv.y * wv.x; acc1.y += xv.y * wv.y; acc1.z += xv.y * wv.z; acc1.w += xv.y * wv.w;
      acc2.x += xv.z * wv.x; acc2.y += xv.z * wv.y; acc2.z += xv.z * wv.z; acc2.w += xv.z * wv.w;
      acc3.x += xv.w * wv.x; acc3.y += xv.w * wv.y; acc3.z += xv.w * wv.z; acc3.w += xv.w * wv.w;
    }
    acc0.x = fmaxf(acc0.x, 0.f); acc0.y = fmaxf(acc0.y, 0.f); acc0.z = fmaxf(acc0.z, 0.f); acc0.w = fmaxf(acc0.w, 0.f);
    acc1.x = fmaxf(acc1.x, 0.f); acc1.y = fmaxf(acc1.y, 0.f); acc1.z = fmaxf(acc1.z, 0.f); acc1.w = fmaxf(acc1.w, 0.f);
    acc2.x = fmaxf(acc2.x, 0.f); acc2.y = fmaxf(acc2.y, 0.f); acc2.z = fmaxf(acc2.z, 0.f); acc2.w = fmaxf(acc2.w, 0.f);
    acc3.x = fmaxf(acc3.x, 0.f); acc3.y = fmaxf(acc3.y, 0.f); acc3.z = fmaxf(acc3.z, 0.f); acc3.w = fmaxf(acc3.w, 0.f);
    *(float4*)&hR[(r0 + 0) * 68 + c0] = acc0;
    *(float4*)&hR[(r0 + 1) * 68 + c0] = acc1;
    *(float4*)&hR[(r0 + 2) * 68 + c0] = acc2;
    *(float4*)&hR[(r0 + 3) * 68 + c0] = acc3;
    __syncthreads();

    // hs = h + A@h: acc_i[c] += sum_j A[r0+i][j] h[j][c]; A[r][j]=A[j][r]
#pragma unroll 8
    for (int j = 0; j < 64; ++j) {
      float4 av = *(const float4*)&Ablk[j * 64 + r0];   // = A[r0..r0+3][j]
      float4 hv = *(const float4*)&hR[j * 68 + c0];
      acc0.x += av.x * hv.x; acc0.y += av.x * hv.y; acc0.z += av.x * hv.z; acc0.w += av.x * hv.w;
      acc1.x += av.y * hv.x; acc1.y += av.y * hv.y; acc1.z += av.y * hv.z; acc1.w += av.y * hv.w;
      acc2.x += av.z * hv.x; acc2.y += av.z * hv.y; acc2.z += av.z * hv.z; acc2.w += av.z * hv.w;
      acc3.x += av.w * hv.x; acc3.y += av.w * hv.y; acc3.z += av.w * hv.z; acc3.w += av.w * hv.w;
    }

    // row L2 norms: partial over this thread's 4 cols, combine across 16 cg
    prt[(r0 + 0) * 17 + cg] = acc0.x*acc0.x + acc0.y*acc0.y + acc0.z*acc0.z + acc0.w*acc0.w;
    prt[(r0 + 1) * 17 + cg] = acc1.x*acc1.x + acc1.y*acc1.y + acc1.z*acc1.z + acc1.w*acc1.w;
    prt[(r0 + 2) * 17 + cg] = acc2.x*acc2.x + acc2.y*acc2.y + acc2.z*acc2.z + acc2.w*acc2.w;
    prt[(r0 + 3) * 17 + cg] = acc3.x*acc3.x + acc3.y*acc3.y + acc3.z*acc3.z + acc3.w*acc3.w;
    __syncthreads();
    if (tid < 64) {
      float s = 0.f;
#pragma unroll
      for (int t = 0; t < 16; ++t) s += prt[tid * 17 + t];
      inv64[tid] = 1.0f / fmaxf(sqrtf(s), 1e-12f);
    }
    __syncthreads();
    {
      float i0 = inv64[r0 + 0], i1 = inv64[r0 + 1];
      float i2 = inv64[r0 + 2], i3 = inv64[r0 + 3];
      float4 w0 = {acc0.x * i0, acc1.x * i1, acc2.x * i2, acc3.x * i3};
      float4 w1 = {acc0.y * i0, acc1.y * i1, acc2.y * i2, acc3.y * i3};
      float4 w2 = {acc0.z * i0, acc1.z * i1, acc2.z * i2, acc3.z * i3};
      float4 w3 = {acc0.w * i0, acc1.w * i1, acc2.w * i2, acc3.w * i3};
      *(float4*)&xT[(c0 + 0) * 68 + r0] = w0;   // xT[col][rows r0..r0+3]
      *(float4*)&xT[(c0 + 1) * 68 + r0] = w1;
      *(float4*)&xT[(c0 + 2) * 68 + r0] = w2;
      *(float4*)&xT[(c0 + 3) * 68 + r0] = w3;
    }
    __syncthreads();
  }

  // pool: mol[k] = sum_atoms xT[k][.]
  {
    int k = tid & 63, half = tid >> 6;
    const float* xp = &xT[k * 68 + half * 16];
    float s = 0.f;
#pragma unroll
    for (int i = 0; i < 16; ++i) s += xp[i];
    red[half * 64 + k] = s;
  }
  __syncthreads();
  if (tid < 64) mol[tid] = red[tid] + red[64 + tid] + red[128 + tid] + red[192 + tid];
  __syncthreads();
  if (tid < 64) {
    float a = fc_b[tid];
    const float* wr = fc_w + tid * 64;
#pragma unroll 8
    for (int k = 0; k < 64; ++k) a += mol[k] * wr[k];
    vloc[tid] = a;
    vout[b * 64 + tid] = a;
  }
  __syncthreads();
  if (tid < 192) {   // layer-0 qkv (kernel boundary = barrier)
    const float4* wr = (const float4*)(qkv_w + tid * 64);
    float a = qkv_b[tid];
#pragma unroll
    for (int k4 = 0; k4 < 16; ++k4) {
      float4 w4 = wr[k4];
      float4 x4 = *(const float4*)&vloc[k4 * 4];
      a += w4.x * x4.x + w4.y * x4.y + w4.z * x4.z + w4.w * x4.w;
    }
    qqout[(size_t)b * 192 + tid] = a;
  }
}

// ======================================================================
// K2/K3: attention + FF for one layer; then next-layer qkv or head.
// grid=128 (token), block=512
// ======================================================================
template <bool LAST>
__global__ __launch_bounds__(512) void layer_kernel(
    const float* __restrict__ vin, const float* __restrict__ qq_in,
    const float* __restrict__ out_w, const float* __restrict__ out_b,
    const float* __restrict__ ln1_s, const float* __restrict__ ln1_b,
    const float* __restrict__ w1t, const float* __restrict__ ff1_b,
    const float* __restrict__ ff2_w, const float* __restrict__ ff2_b,
    const float* __restrict__ ln2_s, const float* __restrict__ ln2_b,
    const float* __restrict__ nqkv_w, const float* __restrict__ nqkv_b,
    float* __restrict__ qq_out,
    const float* __restrict__ Wout_w, const float* __restrict__ Wout_b,
    const float* __restrict__ Wprop_w, const float* __restrict__ Wprop_b,
    float* __restrict__ vout)
{
  __shared__ __align__(16) float qloc[192];
  __shared__ __align__(16) float Pl[4 * 132];
  __shared__ __align__(16) float cb[2048];
  __shared__ __align__(16) float redt[512];
  __shared__ __align__(16) float vloc[64];
  __shared__ __align__(16) float vloc2[64];
  __shared__ __align__(16) float osh[64];
  __shared__ __align__(16) float ffp[64];
  __shared__ float w8[8], w8b[8];

  const int b   = blockIdx.x;
  const int tid = threadIdx.x;

  if (tid < 64)  vloc[tid] = vin[b * 64 + tid];
  if (tid < 192) qloc[tid] = qq_in[(size_t)b * 192 + tid];
  __syncthreads();

  // ---- scores + softmax: thread = (j, h) ----
  {
    const int j = tid & 127, h = tid >> 7;
    const float4* qp = (const float4*)&qloc[h * 16];
    const float4* kp = (const float4*)(qq_in + (size_t)j * 192 + 64 + h * 16);
    float s = 0.f;
#pragma unroll
    for (int t = 0; t < 4; ++t) {
      float4 a4 = qp[t], b4 = kp[t];
      s += a4.x * b4.x + a4.y * b4.y + a4.z * b4.z + a4.w * b4.w;
    }
    s *= 0.25f;  // 1/sqrt(16)
    float mm = s;
    for (int off = 32; off; off >>= 1) mm = fmaxf(mm, __shfl_xor(mm, off));
    if ((tid & 63) == 0) w8[tid >> 6] = mm;
    __syncthreads();
    float M = fmaxf(w8[2 * h], w8[2 * h + 1]);
    float e = expf(s - M);
    float sm = e;
    for (int off = 32; off; off >>= 1) sm += __shfl_xor(sm, off);
    if ((tid & 63) == 0) w8b[tid >> 6] = sm;
    __syncthreads();
    Pl[h * 132 + j] = e / (w8b[2 * h] + w8b[2 * h + 1]);
  }
  __syncthreads();

  // ---- PV: thread = (d, j-chunk) ----
  {
    const int d = tid & 63, part = tid >> 6, h2 = d >> 4;
    float a = 0.f;
#pragma unroll
    for (int jj = 0; jj < 16; ++jj) {
      int j2 = part * 16 + jj;
      a += Pl[h2 * 132 + j2] * qq_in[(size_t)j2 * 192 + 128 + d];
    }
    redt[part * 64 + d] = a;
  }
  __syncthreads();
  if (tid < 64) {
    float o = 0.f;
#pragma unroll
    for (int p = 0; p < 8; ++p) o += redt[p * 64 + tid];
    osh[tid] = o;
  }
  __syncthreads();

  // ---- out-proj + residual + LN1 ----
  if (tid < 64) {
    const int d = tid;
    float a = out_b[d];
    const float* wr = out_w + d * 64;
#pragma unroll 8
    for (int c = 0; c < 64; ++c) a += osh[c] * wr[c];
    float r = vloc[d] + a;
    float mu = r;
    for (int off = 32; off; off >>= 1) mu += __shfl_xor(mu, off);
    mu *= (1.0f / 64.0f);
    float df = r - mu;
    float var = df * df;
    for (int off = 32; off; off >>= 1) var += __shfl_xor(var, off);
    var *= (1.0f / 64.0f);
    vloc2[d] = df / sqrtf(var + 1e-5f) * ln1_s[d] + ln1_b[d];
  }
  __syncthreads();

  // ---- FF phase 1: transposed w1 (k-major), coalesced, NO shuffles ----
  {
    const float4* wt = (const float4*)w1t;   // [64][2048/4]
    float4 a0 = {0.f, 0.f, 0.f, 0.f}, a1 = {0.f, 0.f, 0.f, 0.f};
#pragma unroll 8
    for (int k = 0; k < 64; k += 2) {
      float v0 = vloc2[k], v1 = vloc2[k + 1];
      float4 wv0 = wt[(size_t)k * 512 + tid];
      float4 wv1 = wt[(size_t)(k + 1) * 512 + tid];
      a0.x += v0 * wv0.x; a0.y += v0 * wv0.y; a0.z += v0 * wv0.z; a0.w += v0 * wv0.w;
      a1.x += v1 * wv1.x; a1.y += v1 * wv1.y; a1.z += v1 * wv1.z; a1.w += v1 * wv1.w;
    }
    const int j0 = tid * 4;
    float4 bb = *(const float4*)&ff1_b[j0];
    float4 r;
    r.x = fmaxf(a0.x + a1.x + bb.x, 0.f);
    r.y = fmaxf(a0.y + a1.y + bb.y, 0.f);
    r.z = fmaxf(a0.z + a1.z + bb.z, 0.f);
    r.w = fmaxf(a0.w + a1.w + bb.w, 0.f);
    *(float4*)&cb[j0] = r;
  }
  __syncthreads();

  // ---- FF phase 2: wave w owns rows d = w*8..w*8+7, coalesced w2 read ----
  {
    const int w = tid >> 6, lane = tid & 63;
    const float4* w2f = (const float4*)ff2_w;
    const float4* cbf = (const float4*)cb;
#pragma unroll
    for (int rr = 0; rr < 8; ++rr) {
      int d = w * 8 + rr;
      float p = 0.f;
#pragma unroll
      for (int it = 0; it < 8; ++it) {
        int f = it * 64 + lane;
        float4 wv = w2f[d * 512 + f];
        float4 cv = cbf[f];
        p += wv.x * cv.x + wv.y * cv.y + wv.z * cv.z + wv.w * cv.w;
      }
      for (int off = 32; off; off >>= 1) p += __shfl_xor(p, off);
      if (lane == 0) ffp[d] = p;
    }
  }
  __syncthreads();

  // ---- residual + LN2 -> vloc ----
  if (tid < 64) {
    const int d = tid;
    float r = vloc2[d] + ffp[d] + ff2_b[d];
    float mu = r;
    for (int off = 32; off; off >>= 1) mu += __shfl_xor(mu, off);
    mu *= (1.0f / 64.0f);
    float df = r - mu;
    float var = df * df;
    for (int off = 32; off; off >>= 1) var += __shfl_xor(var, off);
    var *= (1.0f / 64.0f);
    vloc[d] = df / sqrtf(var + 1e-5f) * ln2_s[d] + ln2_b[d];
  }
  __syncthreads();

  if (!LAST) {
    if (tid < 64) vout[b * 64 + tid] = vloc[tid];
    if (tid < 192) {
      const float4* wr = (const float4*)(nqkv_w + tid * 64);
      float a = nqkv_b[tid];
#pragma unroll
      for (int k4 = 0; k4 < 16; ++k4) {
        float4 w4 = wr[k4];
        float4 x4 = *(const float4*)&vloc[k4 * 4];
        a += w4.x * x4.x + w4.y * x4.y + w4.z * x4.z + w4.w * x4.w;
      }
      qq_out[(size_t)b * 192 + tid] = a;
    }
  } else {
    float* hh0 = redt;
    float* hh1 = redt + 64;
    if (tid < 64) {
      float a = Wout_b[tid];
      const float* wr = Wout_w + tid * 64;
#pragma unroll 8
      for (int c = 0; c < 64; ++c) a += vloc[c] * wr[c];
      hh0[tid] = fmaxf(a, 0.f);
    }
    __syncthreads();
    if (tid < 64) {
      float a = Wout_b[64 + tid];
      const float* wr = Wout_w + 4096 + tid * 64;
#pragma unroll 8
      for (int c = 0; c < 64; ++c) a += hh0[c] * wr[c];
      hh1[tid] = fmaxf(a, 0.f);
    }
    __syncthreads();
    if (tid < 2) {
      float a = Wprop_b[tid];
      const float* wr = Wprop_w + tid * 64;
#pragma unroll 8
      for (int c = 0; c < 64; ++c) a += hh1[c] * wr[c];
      vout[b * 2 + tid] = a;
    }
  }
}

// ======================================================================
extern "C" void kernel_launch(void* const* d_in, const int* in_sizes, int n_in,
                              void* d_out, int out_size, void* d_ws, size_t ws_size,
                              hipStream_t stream) {
  const int*   fp      = (const int*)  d_in[0];
  const float* Aadj    = (const float*)d_in[1];
  const float* embed   = (const float*)d_in[2];
  const float* Wfp     = (const float*)d_in[3];
  const float* bfp     = (const float*)d_in[4];
  const float* fc_w    = (const float*)d_in[5];
  const float* fc_b    = (const float*)d_in[6];
  const float* qkv_w   = (const float*)d_in[7];
  const float* qkv_b   = (const float*)d_in[8];
  const float* out_w   = (const float*)d_in[9];
  const float* out_b   = (const float*)d_in[10];
  const float* ln1_s   = (const float*)d_in[11];
  const float* ln1_b   = (const float*)d_in[12];
  const float* ff1_w   = (const float*)d_in[13];
  const float* ff1_b   = (const float*)d_in[14];
  const float* ff2_w   = (const float*)d_in[15];
  const float* ff2_b   = (const float*)d_in[16];
  const float* ln2_s   = (const float*)d_in[17];
  const float* ln2_b   = (const float*)d_in[18];
  const float* Wout_w  = (const float*)d_in[19];
  const float* Wout_b  = (const float*)d_in[20];
  const float* Wprop_w = (const float*)d_in[21];
  const float* Wprop_b = (const float*)d_in[22];
  float* out = (float*)d_out;

  float* ws  = (float*)d_ws;
  float* v0  = ws;             // [128][64]
  float* v1  = ws + 8192;      // [128][64]
  float* qq0 = ws + 16384;     // [128][192]
  float* qq1 = ws + 40960;     // [128][192]
  float* wT1 = ws + 65536;     // 2 x [64][2048]

  gnn_kernel<<<dim3(NB + 64), dim3(256), 0, stream>>>(
      fp, Aadj, embed, Wfp, bfp, fc_w, fc_b, qkv_w, qkv_b,
      ff1_w, wT1, v0, qq0);

  layer_kernel<false><<<dim3(NB), dim3(512), 0, stream>>>(
      v0, qq0, out_w, out_b, ln1_s, ln1_b,
      wT1, ff1_b, ff2_w, ff2_b, ln2_s, ln2_b,
      qkv_w + 12288, qkv_b + 192, qq1,
      nullptr, nullptr, nullptr, nullptr, v1);

  layer_kernel<true><<<dim3(NB), dim3(512), 0, stream>>>(
      v1, qq1, out_w + 4096, out_b + 64, ln1_s + 64, ln1_b + 64,
      wT1 + 131072, ff1_b + 2048, ff2_w + 131072, ff2_b + 64,
      ln2_s + 64, ln2_b + 64,
      nullptr, nullptr, nullptr,
      Wout_w, Wout_b, Wprop_w, Wprop_b, out);
}

// Round 5
// 67.979 us; speedup vs baseline: 2.5790x; 1.0012x over previous
//
#include <hip/hip_runtime.h>
#include <cstddef>

#define NB 128   // #molecules / tokens

// bf16 helpers: RNE pack, cheap unpack (low ushort = even elem, high = odd)
__device__ __forceinline__ unsigned short f2bf(float x) {
  unsigned int u = __float_as_uint(x);
  u = (u + 0x7FFFu + ((u >> 16) & 1u)) >> 16;
  return (unsigned short)u;
}
__device__ __forceinline__ float bf_lo(unsigned int w) {   // bits 15:0
  return __uint_as_float(w << 16);
}
__device__ __forceinline__ float bf_hi(unsigned int w) {   // bits 31:16
  return __uint_as_float(w & 0xFFFF0000u);
}

// ======================================================================
// K1: blocks 0..127   : GNN + pool + fc + qkv(layer0)
//     blocks 128..191 : transpose+bf16 ff1_w -> wT1b  [l][k][j] ushort
//     blocks 192..255 : bf16-convert  ff2_w -> w2b    [l][d][f] ushort
// block=256
// ======================================================================
__global__ __launch_bounds__(256) void gnn_kernel(
    const int* __restrict__ fp, const float* __restrict__ Aadj,
    const float* __restrict__ embed, const float* __restrict__ Wfp,
    const float* __restrict__ bfp, const float* __restrict__ fc_w,
    const float* __restrict__ fc_b,
    const float* __restrict__ qkv_w, const float* __restrict__ qkv_b,
    const float* __restrict__ ff1_w, const float* __restrict__ ff2_w,
    unsigned short* __restrict__ wT1b, unsigned short* __restrict__ w2b,
    float* __restrict__ vout, float* __restrict__ qqout)
{
  __shared__ __align__(16) float xT[64 * 68];    // [feat k][atom]
  __shared__ __align__(16) float hR[64 * 68];    // [atom][feat]
  __shared__ __align__(16) float WT[64 * 68];    // [k][o]  (W transposed)
  __shared__ __align__(16) float Ablk[64 * 64];  // [i][j] symmetric
  __shared__ float prt[64 * 17];
  __shared__ float inv64[64];
  __shared__ float red[256];
  __shared__ __align__(16) float mol[64];
  __shared__ __align__(16) float vloc[64];

  const int bid = blockIdx.x;
  const int tid = threadIdx.x;

  // ---------------- w1 transpose + bf16 blocks ----------------
  if (bid >= NB && bid < NB + 64) {
    const int t = bid - NB;            // 0..63
    const int l = t >> 5, j0 = (t & 31) * 64;
    const float* src = ff1_w + (size_t)l * 131072;
    unsigned short* dst = wT1b + (size_t)l * 131072;
#pragma unroll
    for (int q = 0; q < 4; ++q) {      // read coalesced rows j
      int jr = (tid >> 4) + 16 * q, kq = tid & 15;
      float4 vv = *(const float4*)(src + (size_t)(j0 + jr) * 64 + kq * 4);
      *(float4*)&xT[jr * 68 + kq * 4] = vv;
    }
    __syncthreads();
#pragma unroll
    for (int q = 0; q < 4; ++q) {      // write coalesced rows k (bf16)
      int kr = (tid >> 4) + 16 * q, jq = tid & 15;
      ushort4 ov;
      ov.x = f2bf(xT[(jq * 4 + 0) * 68 + kr]);
      ov.y = f2bf(xT[(jq * 4 + 1) * 68 + kr]);
      ov.z = f2bf(xT[(jq * 4 + 2) * 68 + kr]);
      ov.w = f2bf(xT[(jq * 4 + 3) * 68 + kr]);
      *(ushort4*)(dst + (size_t)kr * 2048 + j0 + jq * 4) = ov;
    }
    return;
  }
  // ---------------- w2 bf16-convert blocks ----------------
  if (bid >= NB + 64) {
    const int t = bid - NB - 64;       // 0..63, 4096 floats each
    const float4*  s4 = (const float4*)ff2_w + (size_t)t * 1024;
    ushort4*       d4 = (ushort4*)w2b + (size_t)t * 1024;
#pragma unroll
    for (int q = 0; q < 4; ++q) {
      int i = q * 256 + tid;
      float4 vv = s4[i];
      ushort4 ov = {f2bf(vv.x), f2bf(vv.y), f2bf(vv.z), f2bf(vv.w)};
      d4[i] = ov;
    }
    return;
  }

  // ---------------- GNN blocks ----------------
  const int b  = bid;
  const int rg = tid & 15, cg = tid >> 4;   // 16 row-groups x 16 col-groups
  const int r0 = rg * 4,   c0 = cg * 4;

  for (int idx = tid; idx < 4096; idx += 256) {
    int r = idx >> 6, c = idx & 63;
    xT[c * 68 + r] = embed[(size_t)fp[b * 64 + r] * 64 + c];
  }
  for (int idx = tid; idx < 1024; idx += 256) {
    int r = idx >> 4, q = idx & 15;
    *(float4*)&Ablk[r * 64 + q * 4] =
        *(const float4*)(Aadj + (size_t)(b * 64 + r) * 8192 + b * 64 + q * 4);
  }

  for (int l = 0; l < 3; ++l) {
    for (int idx = tid; idx < 4096; idx += 256) {
      int o = idx >> 6, k = idx & 63;
      WT[k * 68 + o] = Wfp[l * 4096 + o * 64 + k];
    }
    __syncthreads();

    float4 bb = *(const float4*)&bfp[l * 64 + c0];
    float4 acc0 = bb, acc1 = bb, acc2 = bb, acc3 = bb;
#pragma unroll 8
    for (int k = 0; k < 64; ++k) {
      float4 xv = *(const float4*)&xT[k * 68 + r0];
      float4 wv = *(const float4*)&WT[k * 68 + c0];
      acc0.x += xv.x * wv.x; acc0.y += xv.x * wv.y; acc0.z += xv.x * wv.z; acc0.w += xv.x * wv.w;
      acc1.x += xv.y * wv.x; acc1.y += xv.y * wv.y; acc1.z += xv.y * wv.z; acc1.w += xv.y * wv.w;
      acc2.x += xv.z * wv.x; acc2.y += xv.z * wv.y; acc2.z += xv.z * wv.z; acc2.w += xv.z * wv.w;
      acc3.x += xv.w * wv.x; acc3.y += xv.w * wv.y; acc3.z += xv.w * wv.z; acc3.w += xv.w * wv.w;
    }
    acc0.x = fmaxf(acc0.x, 0.f); acc0.y = fmaxf(acc0.y, 0.f); acc0.z = fmaxf(acc0.z, 0.f); acc0.w = fmaxf(acc0.w, 0.f);
    acc1.x = fmaxf(acc1.x, 0.f); acc1.y = fmaxf(acc1.y, 0.f); acc1.z = fmaxf(acc1.z, 0.f); acc1.w = fmaxf(acc1.w, 0.f);
    acc2.x = fmaxf(acc2.x, 0.f); acc2.y = fmaxf(acc2.y, 0.f); acc2.z = fmaxf(acc2.z, 0.f); acc2.w = fmaxf(acc2.w, 0.f);
    acc3.x = fmaxf(acc3.x, 0.f); acc3.y = fmaxf(acc3.y, 0.f); acc3.z = fmaxf(acc3.z, 0.f); acc3.w = fmaxf(acc3.w, 0.f);
    *(float4*)&hR[(r0 + 0) * 68 + c0] = acc0;
    *(float4*)&hR[(r0 + 1) * 68 + c0] = acc1;
    *(float4*)&hR[(r0 + 2) * 68 + c0] = acc2;
    *(float4*)&hR[(r0 + 3) * 68 + c0] = acc3;
    __syncthreads();

#pragma unroll 8
    for (int j = 0; j < 64; ++j) {
      float4 av = *(const float4*)&Ablk[j * 64 + r0];   // A sym: = A[r0..][j]
      float4 hv = *(const float4*)&hR[j * 68 + c0];
      acc0.x += av.x * hv.x; acc0.y += av.x * hv.y; acc0.z += av.x * hv.z; acc0.w += av.x * hv.w;
      acc1.x += av.y * hv.x; acc1.y += av.y * hv.y; acc1.z += av.y * hv.z; acc1.w += av.y * hv.w;
      acc2.x += av.z * hv.x; acc2.y += av.z * hv.y; acc2.z += av.z * hv.z; acc2.w += av.z * hv.w;
      acc3.x += av.w * hv.x; acc3.y += av.w * hv.y; acc3.z += av.w * hv.z; acc3.w += av.w * hv.w;
    }

    prt[(r0 + 0) * 17 + cg] = acc0.x*acc0.x + acc0.y*acc0.y + acc0.z*acc0.z + acc0.w*acc0.w;
    prt[(r0 + 1) * 17 + cg] = acc1.x*acc1.x + acc1.y*acc1.y + acc1.z*acc1.z + acc1.w*acc1.w;
    prt[(r0 + 2) * 17 + cg] = acc2.x*acc2.x + acc2.y*acc2.y + acc2.z*acc2.z + acc2.w*acc2.w;
    prt[(r0 + 3) * 17 + cg] = acc3.x*acc3.x + acc3.y*acc3.y + acc3.z*acc3.z + acc3.w*acc3.w;
    __syncthreads();
    if (tid < 64) {
      float s = 0.f;
#pragma unroll
      for (int t = 0; t < 16; ++t) s += prt[tid * 17 + t];
      inv64[tid] = 1.0f / fmaxf(sqrtf(s), 1e-12f);
    }
    __syncthreads();
    {
      float i0 = inv64[r0 + 0], i1 = inv64[r0 + 1];
      float i2 = inv64[r0 + 2], i3 = inv64[r0 + 3];
      float4 w0 = {acc0.x * i0, acc1.x * i1, acc2.x * i2, acc3.x * i3};
      float4 w1 = {acc0.y * i0, acc1.y * i1, acc2.y * i2, acc3.y * i3};
      float4 w2 = {acc0.z * i0, acc1.z * i1, acc2.z * i2, acc3.z * i3};
      float4 w3 = {acc0.w * i0, acc1.w * i1, acc2.w * i2, acc3.w * i3};
      *(float4*)&xT[(c0 + 0) * 68 + r0] = w0;
      *(float4*)&xT[(c0 + 1) * 68 + r0] = w1;
      *(float4*)&xT[(c0 + 2) * 68 + r0] = w2;
      *(float4*)&xT[(c0 + 3) * 68 + r0] = w3;
    }
    __syncthreads();
  }

  {
    int k = tid & 63, half = tid >> 6;
    const float* xp = &xT[k * 68 + half * 16];
    float s = 0.f;
#pragma unroll
    for (int i = 0; i < 16; ++i) s += xp[i];
    red[half * 64 + k] = s;
  }
  __syncthreads();
  if (tid < 64) mol[tid] = red[tid] + red[64 + tid] + red[128 + tid] + red[192 + tid];
  __syncthreads();
  if (tid < 64) {
    float a = fc_b[tid];
    const float* wr = fc_w + tid * 64;
#pragma unroll 8
    for (int k = 0; k < 64; ++k) a += mol[k] * wr[k];
    vloc[tid] = a;
    vout[b * 64 + tid] = a;
  }
  __syncthreads();
  if (tid < 192) {
    const float4* wr = (const float4*)(qkv_w + tid * 64);
    float a = qkv_b[tid];
#pragma unroll
    for (int k4 = 0; k4 < 16; ++k4) {
      float4 w4 = wr[k4];
      float4 x4 = *(const float4*)&vloc[k4 * 4];
      a += w4.x * x4.x + w4.y * x4.y + w4.z * x4.z + w4.w * x4.w;
    }
    qqout[(size_t)b * 192 + tid] = a;
  }
}

// ======================================================================
// K2/K3: attention + FF (bf16 weights) for one layer; then next-layer
// qkv or head.  grid=128 (token), block=512
// ======================================================================
template <bool LAST>
__global__ __launch_bounds__(512) void layer_kernel(
    const float* __restrict__ vin, const float* __restrict__ qq_in,
    const float* __restrict__ out_w, const float* __restrict__ out_b,
    const float* __restrict__ ln1_s, const float* __restrict__ ln1_b,
    const unsigned short* __restrict__ w1t, const float* __restrict__ ff1_b,
    const unsigned short* __restrict__ w2b, const float* __restrict__ ff2_b,
    const float* __restrict__ ln2_s, const float* __restrict__ ln2_b,
    const float* __restrict__ nqkv_w, const float* __restrict__ nqkv_b,
    float* __restrict__ qq_out,
    const float* __restrict__ Wout_w, const float* __restrict__ Wout_b,
    const float* __restrict__ Wprop_w, const float* __restrict__ Wprop_b,
    float* __restrict__ vout)
{
  __shared__ __align__(16) float qloc[192];
  __shared__ __align__(16) float Pl[4 * 132];
  __shared__ __align__(16) float cb[2048];
  __shared__ __align__(16) float redt[512];
  __shared__ __align__(16) float vloc[64];
  __shared__ __align__(16) float vloc2[64];
  __shared__ __align__(16) float osh[64];
  __shared__ __align__(16) float ffp[64];
  __shared__ float w8[8], w8b[8];

  const int b   = blockIdx.x;
  const int tid = threadIdx.x;

  if (tid < 64)  vloc[tid] = vin[b * 64 + tid];
  if (tid < 192) qloc[tid] = qq_in[(size_t)b * 192 + tid];
  __syncthreads();

  // ---- scores + softmax: thread = (j, h) ----
  {
    const int j = tid & 127, h = tid >> 7;
    const float4* qp = (const float4*)&qloc[h * 16];
    const float4* kp = (const float4*)(qq_in + (size_t)j * 192 + 64 + h * 16);
    float s = 0.f;
#pragma unroll
    for (int t = 0; t < 4; ++t) {
      float4 a4 = qp[t], b4 = kp[t];
      s += a4.x * b4.x + a4.y * b4.y + a4.z * b4.z + a4.w * b4.w;
    }
    s *= 0.25f;  // 1/sqrt(16)
    float mm = s;
    for (int off = 32; off; off >>= 1) mm = fmaxf(mm, __shfl_xor(mm, off));
    if ((tid & 63) == 0) w8[tid >> 6] = mm;
    __syncthreads();
    float M = fmaxf(w8[2 * h], w8[2 * h + 1]);
    float e = expf(s - M);
    float sm = e;
    for (int off = 32; off; off >>= 1) sm += __shfl_xor(sm, off);
    if ((tid & 63) == 0) w8b[tid >> 6] = sm;
    __syncthreads();
    Pl[h * 132 + j] = e / (w8b[2 * h] + w8b[2 * h + 1]);
  }
  __syncthreads();

  // ---- PV: thread = (d, j-chunk) ----
  {
    const int d = tid & 63, part = tid >> 6, h2 = d >> 4;
    float a = 0.f;
#pragma unroll
    for (int jj = 0; jj < 16; ++jj) {
      int j2 = part * 16 + jj;
      a += Pl[h2 * 132 + j2] * qq_in[(size_t)j2 * 192 + 128 + d];
    }
    redt[part * 64 + d] = a;
  }
  __syncthreads();
  if (tid < 64) {
    float o = 0.f;
#pragma unroll
    for (int p = 0; p < 8; ++p) o += redt[p * 64 + tid];
    osh[tid] = o;
  }
  __syncthreads();

  // ---- out-proj + residual + LN1 ----
  if (tid < 64) {
    const int d = tid;
    float a = out_b[d];
    const float* wr = out_w + d * 64;
#pragma unroll 8
    for (int c = 0; c < 64; ++c) a += osh[c] * wr[c];
    float r = vloc[d] + a;
    float mu = r;
    for (int off = 32; off; off >>= 1) mu += __shfl_xor(mu, off);
    mu *= (1.0f / 64.0f);
    float df = r - mu;
    float var = df * df;
    for (int off = 32; off; off >>= 1) var += __shfl_xor(var, off);
    var *= (1.0f / 64.0f);
    vloc2[d] = df / sqrtf(var + 1e-5f) * ln1_s[d] + ln1_b[d];
  }
  __syncthreads();

  // ---- FF phase 1: bf16 transposed w1 (k-major), coalesced ----
  {
    const uint2* wt = (const uint2*)w1t;   // row k: 512 x uint2 (4 bf16)
    float4 a0 = {0.f, 0.f, 0.f, 0.f}, a1 = {0.f, 0.f, 0.f, 0.f};
#pragma unroll 8
    for (int k = 0; k < 64; k += 2) {
      float v0 = vloc2[k], v1 = vloc2[k + 1];
      uint2 w0 = wt[(size_t)k * 512 + tid];
      uint2 w1v = wt[(size_t)(k + 1) * 512 + tid];
      a0.x += v0 * bf_lo(w0.x); a0.y += v0 * bf_hi(w0.x);
      a0.z += v0 * bf_lo(w0.y); a0.w += v0 * bf_hi(w0.y);
      a1.x += v1 * bf_lo(w1v.x); a1.y += v1 * bf_hi(w1v.x);
      a1.z += v1 * bf_lo(w1v.y); a1.w += v1 * bf_hi(w1v.y);
    }
    const int j0 = tid * 4;
    float4 bb = *(const float4*)&ff1_b[j0];
    float4 r;
    r.x = fmaxf(a0.x + a1.x + bb.x, 0.f);
    r.y = fmaxf(a0.y + a1.y + bb.y, 0.f);
    r.z = fmaxf(a0.z + a1.z + bb.z, 0.f);
    r.w = fmaxf(a0.w + a1.w + bb.w, 0.f);
    *(float4*)&cb[j0] = r;
  }
  __syncthreads();

  // ---- FF phase 2: bf16 w2, wave w owns rows d = w*8..w*8+7 ----
  {
    const int w = tid >> 6, lane = tid & 63;
    const uint4* w2f = (const uint4*)w2b;    // row d: 256 x uint4 (8 bf16)
    const float4* cbf = (const float4*)cb;
#pragma unroll
    for (int rr = 0; rr < 8; ++rr) {
      int d = w * 8 + rr;
      float p = 0.f;
#pragma unroll
      for (int it = 0; it < 4; ++it) {
        int fb = it * 64 + lane;             // ushort8-chunk index
        uint4 wv = w2f[(size_t)d * 256 + fb];
        float4 c0 = cbf[fb * 2], c1 = cbf[fb * 2 + 1];
        p += bf_lo(wv.x) * c0.x + bf_hi(wv.x) * c0.y
           + bf_lo(wv.y) * c0.z + bf_hi(wv.y) * c0.w
           + bf_lo(wv.z) * c1.x + bf_hi(wv.z) * c1.y
           + bf_lo(wv.w) * c1.z + bf_hi(wv.w) * c1.w;
      }
      for (int off = 32; off; off >>= 1) p += __shfl_xor(p, off);
      if (lane == 0) ffp[d] = p;
    }
  }
  __syncthreads();

  // ---- residual + LN2 -> vloc ----
  if (tid < 64) {
    const int d = tid;
    float r = vloc2[d] + ffp[d] + ff2_b[d];
    float mu = r;
    for (int off = 32; off; off >>= 1) mu += __shfl_xor(mu, off);
    mu *= (1.0f / 64.0f);
    float df = r - mu;
    float var = df * df;
    for (int off = 32; off; off >>= 1) var += __shfl_xor(var, off);
    var *= (1.0f / 64.0f);
    vloc[d] = df / sqrtf(var + 1e-5f) * ln2_s[d] + ln2_b[d];
  }
  __syncthreads();

  if (!LAST) {
    if (tid < 64) vout[b * 64 + tid] = vloc[tid];
    if (tid < 192) {
      const float4* wr = (const float4*)(nqkv_w + tid * 64);
      float a = nqkv_b[tid];
#pragma unroll
      for (int k4 = 0; k4 < 16; ++k4) {
        float4 w4 = wr[k4];
        float4 x4 = *(const float4*)&vloc[k4 * 4];
        a += w4.x * x4.x + w4.y * x4.y + w4.z * x4.z + w4.w * x4.w;
      }
      qq_out[(size_t)b * 192 + tid] = a;
    }
  } else {
    float* hh0 = redt;
    float* hh1 = redt + 64;
    if (tid < 64) {
      float a = Wout_b[tid];
      const float* wr = Wout_w + tid * 64;
#pragma unroll 8
      for (int c = 0; c < 64; ++c) a += vloc[c] * wr[c];
      hh0[tid] = fmaxf(a, 0.f);
    }
    __syncthreads();
    if (tid < 64) {
      float a = Wout_b[64 + tid];
      const float* wr = Wout_w + 4096 + tid * 64;
#pragma unroll 8
      for (int c = 0; c < 64; ++c) a += hh0[c] * wr[c];
      hh1[tid] = fmaxf(a, 0.f);
    }
    __syncthreads();
    if (tid < 2) {
      float a = Wprop_b[tid];
      const float* wr = Wprop_w + tid * 64;
#pragma unroll 8
      for (int c = 0; c < 64; ++c) a += hh1[c] * wr[c];
      vout[b * 2 + tid] = a;
    }
  }
}

// ======================================================================
extern "C" void kernel_launch(void* const* d_in, const int* in_sizes, int n_in,
                              void* d_out, int out_size, void* d_ws, size_t ws_size,
                              hipStream_t stream) {
  const int*   fp      = (const int*)  d_in[0];
  const float* Aadj    = (const float*)d_in[1];
  const float* embed   = (const float*)d_in[2];
  const float* Wfp     = (const float*)d_in[3];
  const float* bfp     = (const float*)d_in[4];
  const float* fc_w    = (const float*)d_in[5];
  const float* fc_b    = (const float*)d_in[6];
  const float* qkv_w   = (const float*)d_in[7];
  const float* qkv_b   = (const float*)d_in[8];
  const float* out_w   = (const float*)d_in[9];
  const float* out_b   = (const float*)d_in[10];
  const float* ln1_s   = (const float*)d_in[11];
  const float* ln1_b   = (const float*)d_in[12];
  const float* ff1_w   = (const float*)d_in[13];
  const float* ff1_b   = (const float*)d_in[14];
  const float* ff2_w   = (const float*)d_in[15];
  const float* ff2_b   = (const float*)d_in[16];
  const float* ln2_s   = (const float*)d_in[17];
  const float* ln2_b   = (const float*)d_in[18];
  const float* Wout_w  = (const float*)d_in[19];
  const float* Wout_b  = (const float*)d_in[20];
  const float* Wprop_w = (const float*)d_in[21];
  const float* Wprop_b = (const float*)d_in[22];
  float* out = (float*)d_out;

  float* ws  = (float*)d_ws;
  float* v0  = ws;             // [128][64]
  float* v1  = ws + 8192;      // [128][64]
  float* qq0 = ws + 16384;     // [128][192]
  float* qq1 = ws + 40960;     // [128][192]
  unsigned short* wT1b = (unsigned short*)(ws + 65536);   // 2x[64][2048] bf16
  unsigned short* w2b  = wT1b + 262144;                   // 2x[64][2048] bf16

  gnn_kernel<<<dim3(NB + 128), dim3(256), 0, stream>>>(
      fp, Aadj, embed, Wfp, bfp, fc_w, fc_b, qkv_w, qkv_b,
      ff1_w, ff2_w, wT1b, w2b, v0, qq0);

  layer_kernel<false><<<dim3(NB), dim3(512), 0, stream>>>(
      v0, qq0, out_w, out_b, ln1_s, ln1_b,
      wT1b, ff1_b, w2b, ff2_b, ln2_s, ln2_b,
      qkv_w + 12288, qkv_b + 192, qq1,
      nullptr, nullptr, nullptr, nullptr, v1);

  layer_kernel<true><<<dim3(NB), dim3(512), 0, stream>>>(
      v1, qq1, out_w + 4096, out_b + 64, ln1_s + 64, ln1_b + 64,
      wT1b + 131072, ff1_b + 2048, w2b + 131072, ff2_b + 64,
      ln2_s + 64, ln2_b + 64,
      nullptr, nullptr, nullptr,
      Wout_w, Wout_b, Wprop_w, Wprop_b, out);
}